// Round 7
// baseline (122.147 us; speedup 1.0000x reference)
//
#include <hip/hip_runtime.h>
#include <hip/hip_bf16.h>
#include <stdint.h>

// Problem constants
#define NC 512     // NUM_CLASSES
#define FD 1024    // FEAT_DIM
#define NB 64      // BATCH
#define SMOOTH_ 0.01f
#define STQ 40     // Bt row stride in u16 (32 data + 8 pad): 80 B rows, 16B-aligned

typedef __bf16 bf16x8 __attribute__((ext_vector_type(8)));
typedef float f32x4 __attribute__((ext_vector_type(4)));

__device__ __forceinline__ unsigned short f2bf(float f) {
    __hip_bfloat16 h = __float2bfloat16(f);
    return __builtin_bit_cast(unsigned short, h);
}
__device__ __forceinline__ float bf2f(unsigned short u) {
    unsigned int v = (unsigned int)u << 16;
    return __builtin_bit_cast(float, v);
}

__device__ __forceinline__ void gload_lds16(const void* g, void* l) {
    __builtin_amdgcn_global_load_lds(
        (const __attribute__((address_space(1))) void*)(uintptr_t)g,
        (__attribute__((address_space(3))) void*)(uint32_t)(uintptr_t)l,
        16, 0, 0);
}

// ---------------------------------------------------------------------------
// K1: build edge weights ew[512][512], store as bf16 bits. (unchanged, verified)
// ---------------------------------------------------------------------------
__global__ __launch_bounds__(256) void build_ew(
    const float* __restrict__ co, const float* __restrict__ counts,
    const float* __restrict__ emb, unsigned short* __restrict__ ew) {
    __shared__ float s_counts[NC];
    __shared__ float s_nemb[NC * 4];
    __shared__ float s_redA[4], s_redM[4], s_redS[4];
    const int i = blockIdx.x;
    const int t = threadIdx.x;
    const int lane = t & 63, wv = t >> 6;

    float c0 = counts[t], c1 = counts[t + 256];
    s_counts[t] = c0;
    s_counts[t + 256] = c1;
    for (int r = t; r < NC; r += 256) {
        float e0 = emb[r * 4 + 0], e1 = emb[r * 4 + 1];
        float e2 = emb[r * 4 + 2], e3 = emb[r * 4 + 3];
        float inv = 1.0f / sqrtf(e0 * e0 + e1 * e1 + e2 * e2 + e3 * e3);
        s_nemb[r * 4 + 0] = e0 * inv;
        s_nemb[r * 4 + 1] = e1 * inv;
        s_nemb[r * 4 + 2] = e2 * inv;
        s_nemb[r * 4 + 3] = e3 * inv;
    }
    float p = c0 + c1;
#pragma unroll
    for (int o = 32; o; o >>= 1) p += __shfl_down(p, o);
    if (lane == 0) s_redA[wv] = p;
    __syncthreads();
    const float avg = (s_redA[0] + s_redA[1] + s_redA[2] + s_redA[3]) * (1.0f / 512.0f);

    const float ci = s_counts[i];
    const float ni0 = s_nemb[i * 4 + 0], ni1 = s_nemb[i * 4 + 1];
    const float ni2 = s_nemb[i * 4 + 2], ni3 = s_nemb[i * 4 + 3];

    float v[2];
#pragma unroll
    for (int u = 0; u < 2; ++u) {
        const int j = t + u * 256;
        const float c = co[i * NC + j];
        const float cj = s_counts[j];
        const float nco = (c + SMOOTH_) / sqrtf((ci + SMOOTH_) * (cj + SMOOTH_));
        const float sim = ni0 * s_nemb[j * 4 + 0] + ni1 * s_nemb[j * 4 + 1] +
                          ni2 * s_nemb[j * 4 + 2] + ni3 * s_nemb[j * 4 + 3];
        const float aff = sim / (1.0f + expf(-(sim - 0.5f) * 10.0f));
        const float mn = fminf(ci, cj), mx = fmaxf(ci, cj);
        const float bal = (mn > SMOOTH_ && mx > SMOOTH_)
                              ? log1pf(mx / avg) * (mn / mx)
                              : SMOOTH_;
        const float conf = 2.0f / (1.0f + expf(-c * 0.2f)) - 1.0f;
        const float e = (j == i) ? 0.0f : nco * aff * bal * conf;
        v[u] = e * 5.0f;
    }
    float m = fmaxf(v[0], v[1]);
#pragma unroll
    for (int o = 32; o; o >>= 1) m = fmaxf(m, __shfl_down(m, o));
    if (lane == 0) s_redM[wv] = m;
    __syncthreads();
    const float rowmax = fmaxf(fmaxf(s_redM[0], s_redM[1]), fmaxf(s_redM[2], s_redM[3]));
    const float e0 = expf(v[0] - rowmax), e1 = expf(v[1] - rowmax);
    float s = e0 + e1;
#pragma unroll
    for (int o = 32; o; o >>= 1) s += __shfl_down(s, o);
    if (lane == 0) s_redS[wv] = s;
    __syncthreads();
    const float scale = 0.9f / (s_redS[0] + s_redS[1] + s_redS[2] + s_redS[3]);
    const float w0 = e0 * scale + ((t == i) ? 0.1f : 0.0f);
    const float w1 = e1 * scale + ((t + 256 == i) ? 0.1f : 0.0f);
    ew[i * NC + t] = f2bf(w0);
    ew[i * NC + t + 256] = f2bf(w1);
}

// ---------------------------------------------------------------------------
// K2: GEMM with in-kernel transpose + T4 counted-vmcnt pipeline.
// x_t[b,i,d] = sum_j ew[i,j]*x[b,j,d], written bf16 to ws.
// Per K-step (ONE sync point, at top):
//   s_waitcnt vmcnt(16) lgkmcnt(0)   // retires the 2 A-gloads of the PREV
//                                    // step; the 16 B reg-loads stay in
//                                    // flight across the barrier (T4)
//   s_barrier                        // raw: no implicit drain
//   STAGE_A(s+1 -> p^1)  [2 gload_lds, issued FIRST; sched_barrier pins]
//   STAGE_B(p^1)         [consumes rb (compiler-waited), 8 ds_write_b32]
//   LOAD_B(s+2)          [16 reg loads, issued AFTER the gloads]
//   COMPUTE(p)           [8 ds_read_b128 + 16 MFMA]
// Safety: stage(p^1) only after the barrier; compute(p) before the next
// barrier; each wave's own vmcnt-retire + lgkmcnt(0) precede its barrier ->
// buffers disjoint across waves (same contract as the verified R5/R6 and
// m201 schedules). Last step uses vmcnt(0).
// B LDS tile transposed-on-write: Bt[128 d][STQ=40], write banks uniform
// (free), read = 1 ds_read_b128/frag (free). A path/MFMA/epilogue: proven.
// Grid 2048 = 64 b x (4 i x 8 d), XCD-swizzled (32 blocks of b per XCD).
// ---------------------------------------------------------------------------
__global__ __launch_bounds__(256) void gemm_tr2(
    const unsigned short* __restrict__ ew, const float* __restrict__ x,
    unsigned short* __restrict__ xt) {
    __shared__ __align__(16) unsigned short smA[2][128 * 32];   // 2 x 8 KB
    __shared__ __align__(16) unsigned short smT[2][128 * STQ];  // 2 x 10 KB
    const int t = threadIdx.x;
    const int lane = t & 63, w = t >> 6;
    const int wr = w >> 1, wc = w & 1;

    const int bid = blockIdx.x;
    const int slot = bid & 7, idx = bid >> 3;  // slot = XCD
    const int bq = idx >> 5, inner = idx & 31;
    const int b = slot + bq * 8;               // b % 8 == XCD
    const int i_t = inner >> 3, d_t = inner & 7;
    const int i0 = i_t * 128, d0 = d_t * 128;

    // A staging addresses (proven pattern)
    const unsigned short* gA = ew + (size_t)(i0 + (t >> 2)) * NC + (t & 3) * 8;

    // B loading map: jp = t>>4 (j-pair 0..15), m = t&15 (d residue)
    const int jp = t >> 4, m = t & 15;
    const float* gB0 = x + ((size_t)(b * NC) + 2 * jp) * FD + d0 + m;  // j even
    const float* gB1 = gB0 + FD;                                       // j odd

    const int lr = lane & 15, kidx = lane >> 4;

    f32x4 acc[4][4];
#pragma unroll
    for (int mi = 0; mi < 4; ++mi)
#pragma unroll
        for (int ni = 0; ni < 4; ++ni) acc[mi][ni] = (f32x4){0.f, 0.f, 0.f, 0.f};

    float r0[8], r1[8];  // prefetched x: r0 = j even, r1 = j odd; d = m+16e

    auto LOAD_B = [&](int s) {
        const size_t off = (size_t)s * 32 * FD;
#pragma unroll
        for (int e = 0; e < 8; ++e) {
            r0[e] = gB0[off + 16 * e];
            r1[e] = gB1[off + 16 * e];
        }
    };
    auto STAGE_A = [&](int s, int pb) {
        const int k0 = s * 32;
        gload_lds16(gA + k0, &smA[pb][t * 8]);
        gload_lds16(gA + (size_t)64 * NC + k0, &smA[pb][64 * 32 + t * 8]);
    };
    auto STAGE_B = [&](int pb) {  // transposed write: Bt[d][j], 8x b32
        unsigned int* bt32 = reinterpret_cast<unsigned int*>(smT[pb]);
#pragma unroll
        for (int e = 0; e < 8; ++e) {
            const int d = m + 16 * e;
            const unsigned int val =
                (unsigned int)f2bf(r0[e]) | ((unsigned int)f2bf(r1[e]) << 16);
            bt32[d * (STQ / 2) + jp] = val;
        }
    };

    // ---- prologue: stage tile 0 into buf 0; prefetch tile 1 ----
    LOAD_B(0);
    STAGE_A(0, 0);
    __builtin_amdgcn_sched_barrier(0);
    STAGE_B(0);       // compiler waits for rb (tile 0) itself
    LOAD_B(1);

    int p = 0;
    for (int s = 0; s < 16; ++s) {
        if (s == 15) {
            asm volatile("s_waitcnt vmcnt(0) lgkmcnt(0)" ::: "memory");
        } else {
            asm volatile("s_waitcnt vmcnt(16) lgkmcnt(0)" ::: "memory");
        }
        __builtin_amdgcn_sched_barrier(0);
        __builtin_amdgcn_s_barrier();

        if (s < 15) {
            STAGE_A(s + 1, p ^ 1);                 // 2 gload_lds first
            __builtin_amdgcn_sched_barrier(0);     // pin: gloads before B loads
            STAGE_B(p ^ 1);                        // consumes rb = tile s+1
        }
        if (s < 14) LOAD_B(s + 2);                 // stays in flight past barrier

        // A fragments (proven: linear [row][32k], bf16x8 at kidx*8)
        const bf16x8* A8 = reinterpret_cast<const bf16x8*>(smA[p]);
        bf16x8 aF[4];
#pragma unroll
        for (int mi = 0; mi < 4; ++mi)
            aF[mi] = A8[(wr * 64 + mi * 16 + lr) * 4 + kidx];
        // B fragments: one b128 each from transposed tile
        bf16x8 bF[4];
#pragma unroll
        for (int ni = 0; ni < 4; ++ni) {
            const int nb = wc * 64 + ni * 16 + lr;
            bF[ni] = *reinterpret_cast<const bf16x8*>(&smT[p][nb * STQ + kidx * 8]);
        }
#pragma unroll
        for (int mi = 0; mi < 4; ++mi)
#pragma unroll
            for (int ni = 0; ni < 4; ++ni)
                acc[mi][ni] = __builtin_amdgcn_mfma_f32_16x16x32_bf16(
                    aF[mi], bF[ni], acc[mi][ni], 0, 0, 0);
        p ^= 1;
    }

    // epilogue: x_t bf16 -> ws. C/D layout: col = lane&15, row = (lane>>4)*4+r
    const int r0e = (lane >> 4) * 4;
#pragma unroll
    for (int mi = 0; mi < 4; ++mi)
#pragma unroll
        for (int ni = 0; ni < 4; ++ni)
#pragma unroll
            for (int r = 0; r < 4; ++r) {
                const size_t R = (size_t)(b * NC + i0 + wr * 64 + mi * 16 + r0e + r);
                xt[R * FD + d0 + wc * 64 + ni * 16 + lr] = f2bf(acc[mi][ni][r]);
            }
}

// ---------------------------------------------------------------------------
// K3: gate. One block per (b,i) row: g = sigmoid(dot(x, x_t)/32);
// out = x*(1-g) + x_t*g. x_t read as bf16 from ws. (proven)
// ---------------------------------------------------------------------------
__global__ __launch_bounds__(256) void gate_out(
    const float* __restrict__ x, const unsigned short* __restrict__ xt,
    float* __restrict__ out) {
    __shared__ float s[4];
    const int row = blockIdx.x;
    const int t = threadIdx.x;
    const size_t base = (size_t)row * FD + t * 4;
    const float4 xv = *reinterpret_cast<const float4*>(x + base);
    const ushort4 uv = *reinterpret_cast<const ushort4*>(xt + base);
    const float t0 = bf2f(uv.x), t1 = bf2f(uv.y), t2 = bf2f(uv.z), t3 = bf2f(uv.w);
    float p = xv.x * t0 + xv.y * t1 + xv.z * t2 + xv.w * t3;
#pragma unroll
    for (int o = 32; o; o >>= 1) p += __shfl_down(p, o);
    if ((t & 63) == 0) s[t >> 6] = p;
    __syncthreads();
    const float dot = s[0] + s[1] + s[2] + s[3];
    const float g = 1.0f / (1.0f + expf(-dot * 0.03125f));
    float4 ov;
    ov.x = xv.x * (1.0f - g) + t0 * g;
    ov.y = xv.y * (1.0f - g) + t1 * g;
    ov.z = xv.z * (1.0f - g) + t2 * g;
    ov.w = xv.w * (1.0f - g) + t3 * g;
    *reinterpret_cast<float4*>(out + base) = ov;
}

extern "C" void kernel_launch(void* const* d_in, const int* in_sizes, int n_in,
                              void* d_out, int out_size, void* d_ws, size_t ws_size,
                              hipStream_t stream) {
    const float* x = (const float*)d_in[0];
    const float* co = (const float*)d_in[1];
    const float* counts = (const float*)d_in[2];
    const float* emb = (const float*)d_in[3];
    float* out = (float*)d_out;

    unsigned short* ew = (unsigned short*)d_ws;                        // 512 KB
    unsigned short* xt = (unsigned short*)((char*)d_ws + (1u << 20));  // 64 MiB

    build_ew<<<NC, 256, 0, stream>>>(co, counts, emb, ew);
    gemm_tr2<<<2048, 256, 0, stream>>>(ew, x, xt);
    gate_out<<<NB * NC, 256, 0, stream>>>(x, xt, out);
}